// Round 1
// baseline (1623.103 us; speedup 1.0000x reference)
//
#include <hip/hip_runtime.h>
#include <math.h>

// ---------------- shapes ----------------
// x:      (16, 3,16,128,128)
// y1:     (16, 4, 8, 64, 64)   conv1 k4 s2 p1 + relu
// y2:     (16, 8, 4, 32, 32)   conv2 k4 s2 p1 + relu
// z:      (16,16, 4, 32, 32)   conv4 k3 s1 p1 + clip(0,6)
// quant:  (16,16, 4, 32, 32)   VQ
// d1:     (16, 8, 8, 64, 64)   deconv1 k4 s2 p1 + relu
// d2:     (16, 4,16,128,128)   deconv3 k4 s2 p1 + relu
// out:    (16, 3,16,128,128)   deconv4 k3 s1 p1

#define NB 16

__global__ __launch_bounds__(256) void conv1_k(
    const float* __restrict__ x, const float* __restrict__ w,
    const float* __restrict__ bias, float* __restrict__ y) {
  int idx = blockIdx.x * blockDim.x + threadIdx.x;
  const int total = NB * 4 * 8 * 64 * 64;
  if (idx >= total) return;
  int ow = idx & 63; int t = idx >> 6;
  int oh = t & 63; t >>= 6;
  int od = t & 7;  t >>= 3;
  int co = t & 3;  int n = t >> 2;
  float acc = bias[co];
  for (int ci = 0; ci < 3; ci++) {
    const float* xp = x + ((n * 3 + ci) * 16) * 16384;
    const float* wp = w + ((co * 3 + ci) * 64);
    #pragma unroll
    for (int kd = 0; kd < 4; kd++) {
      int id = od * 2 - 1 + kd; if ((unsigned)id >= 16u) continue;
      #pragma unroll
      for (int kh = 0; kh < 4; kh++) {
        int ih = oh * 2 - 1 + kh; if ((unsigned)ih >= 128u) continue;
        #pragma unroll
        for (int kw = 0; kw < 4; kw++) {
          int iw = ow * 2 - 1 + kw; if ((unsigned)iw >= 128u) continue;
          acc += xp[id * 16384 + ih * 128 + iw] * wp[kd * 16 + kh * 4 + kw];
        }
      }
    }
  }
  y[idx] = fmaxf(acc, 0.0f);
}

__global__ __launch_bounds__(256) void conv2_k(
    const float* __restrict__ y1, const float* __restrict__ w,
    const float* __restrict__ bias, float* __restrict__ y) {
  int idx = blockIdx.x * blockDim.x + threadIdx.x;
  const int total = NB * 8 * 4 * 32 * 32;
  if (idx >= total) return;
  int ow = idx & 31; int t = idx >> 5;
  int oh = t & 31; t >>= 5;
  int od = t & 3;  t >>= 2;
  int co = t & 7;  int n = t >> 3;
  float acc = bias[co];
  for (int ci = 0; ci < 4; ci++) {
    const float* ip = y1 + ((n * 4 + ci) * 8) * 4096;
    const float* wp = w + ((co * 4 + ci) * 64);
    #pragma unroll
    for (int kd = 0; kd < 4; kd++) {
      int id = od * 2 - 1 + kd; if ((unsigned)id >= 8u) continue;
      #pragma unroll
      for (int kh = 0; kh < 4; kh++) {
        int ih = oh * 2 - 1 + kh; if ((unsigned)ih >= 64u) continue;
        #pragma unroll
        for (int kw = 0; kw < 4; kw++) {
          int iw = ow * 2 - 1 + kw; if ((unsigned)iw >= 64u) continue;
          acc += ip[id * 4096 + ih * 64 + iw] * wp[kd * 16 + kh * 4 + kw];
        }
      }
    }
  }
  y[idx] = fmaxf(acc, 0.0f);
}

__global__ __launch_bounds__(256) void conv4_k(
    const float* __restrict__ y2, const float* __restrict__ w,
    const float* __restrict__ bias, float* __restrict__ z) {
  int idx = blockIdx.x * blockDim.x + threadIdx.x;
  const int total = NB * 16 * 4 * 32 * 32;
  if (idx >= total) return;
  int ow = idx & 31; int t = idx >> 5;
  int oh = t & 31; t >>= 5;
  int od = t & 3;  t >>= 2;
  int co = t & 15; int n = t >> 4;
  float acc = bias[co];
  for (int ci = 0; ci < 8; ci++) {
    const float* ip = y2 + ((n * 8 + ci) * 4) * 1024;
    const float* wp = w + ((co * 8 + ci) * 27);
    #pragma unroll
    for (int kd = 0; kd < 3; kd++) {
      int id = od - 1 + kd; if ((unsigned)id >= 4u) continue;
      #pragma unroll
      for (int kh = 0; kh < 3; kh++) {
        int ih = oh - 1 + kh; if ((unsigned)ih >= 32u) continue;
        #pragma unroll
        for (int kw = 0; kw < 3; kw++) {
          int iw = ow - 1 + kw; if ((unsigned)iw >= 32u) continue;
          acc += ip[id * 1024 + ih * 32 + iw] * wp[kd * 9 + kh * 3 + kw];
        }
      }
    }
  }
  z[idx] = fminf(fmaxf(acc, 0.0f), 6.0f);
}

// VQ: one thread per spatial location. N = 16*4*32*32 = 65536.
// stats[0] = sum (q-z)^2 ; stats[1..32] = histogram
__global__ __launch_bounds__(256) void vq_k(
    const float* __restrict__ z, const float* __restrict__ emb,
    float* __restrict__ quant, float* __restrict__ codes_out,
    float* __restrict__ stats) {
  __shared__ float se[32 * 16];
  __shared__ float se2[32];
  __shared__ float shist[32];
  __shared__ float swred[4];
  int tid = threadIdx.x;
  for (int i = tid; i < 512; i += 256) {
    int r = i >> 4;
    float v = emb[i];
    if (r == 0) v = 0.0f;
    else if (r == 1) v = 6.0f;
    se[i] = v;
  }
  if (tid < 32) shist[tid] = 0.0f;
  __syncthreads();
  if (tid < 32) {
    float s = 0.0f;
    #pragma unroll
    for (int d = 0; d < 16; d++) { float v = se[tid * 16 + d]; s += v * v; }
    se2[tid] = s;
  }
  __syncthreads();

  int idx = blockIdx.x * 256 + tid;  // (b, d, h, w) flat; total 65536
  float lsum = 0.0f;
  {
    int w_ = idx & 31; int t = idx >> 5;
    int h_ = t & 31; t >>= 5;
    int d_ = t & 3;  int b_ = t >> 2;
    const float* zp = z + b_ * 65536 + d_ * 1024 + h_ * 32 + w_;
    float f[16];
    float f2 = 0.0f;
    #pragma unroll
    for (int c = 0; c < 16; c++) { float v = zp[c * 4096]; f[c] = v; f2 += v * v; }
    float best = 1e30f; int bi = 0;
    for (int e = 0; e < 32; e++) {
      float dot = 0.0f;
      #pragma unroll
      for (int c = 0; c < 16; c++) dot += f[c] * se[e * 16 + c];
      float d2 = f2 - 2.0f * dot + se2[e];
      if (d2 < best) { best = d2; bi = e; }
    }
    float* qp = quant + b_ * 65536 + d_ * 1024 + h_ * 32 + w_;
    #pragma unroll
    for (int c = 0; c < 16; c++) {
      float q = se[bi * 16 + c];
      qp[c * 4096] = q;
      float df = q - f[c];
      lsum += df * df;
    }
    codes_out[idx] = (float)bi;
    atomicAdd(&shist[bi], 1.0f);
  }
  // block reduce lsum (4 waves of 64)
  for (int o = 32; o; o >>= 1) lsum += __shfl_down(lsum, o);
  if ((tid & 63) == 0) swred[tid >> 6] = lsum;
  __syncthreads();
  if (tid == 0) atomicAdd(&stats[0], swred[0] + swred[1] + swred[2] + swred[3]);
  if (tid < 32) {
    float h = shist[tid];
    if (h != 0.0f) atomicAdd(&stats[1 + tid], h);
  }
}

__global__ void init_stats_k(float* __restrict__ stats) {
  int tid = threadIdx.x;
  if (tid < 33) stats[tid] = 0.0f;
}

__global__ void fin_k(const float* __restrict__ stats,
                      const float* __restrict__ cluster_size,
                      float* __restrict__ out_loss, float* __restrict__ out_perp,
                      float* __restrict__ out_used) {
  int tid = threadIdx.x;  // one wave of 64
  float v = 0.0f;
  float used = 0.0f;
  if (tid < 32) {
    float p = stats[1 + tid] * (1.0f / 65536.0f);
    v = p * logf(p + 1e-10f);
    used = (cluster_size[tid] > 1e-5f) ? 1.0f : 0.0f;
  }
  for (int o = 16; o; o >>= 1) { v += __shfl_down(v, o); used += __shfl_down(used, o); }
  if (tid == 0) {
    *out_perp = expf(-v);
    *out_used = used * (1.0f / 32.0f);
    *out_loss = 0.25f * stats[0] * (1.0f / 1048576.0f);
  }
}

// deconv1: ConvTranspose3d(16->8, k4, s2, p1): quant (16,16,4,32,32) -> d1 (16,8,8,64,64)
__global__ __launch_bounds__(256) void deconv1_k(
    const float* __restrict__ q, const float* __restrict__ w,
    const float* __restrict__ bias, float* __restrict__ d1) {
  int idx = blockIdx.x * blockDim.x + threadIdx.x;
  const int total = NB * 8 * 8 * 64 * 64;
  if (idx >= total) return;
  int ow = idx & 63; int t = idx >> 6;
  int oh = t & 63; t >>= 6;
  int od = t & 7;  t >>= 3;
  int co = t & 7;  int n = t >> 3;

  int kdv[2], idv[2], nd = 0;
  int khv[2], ihv[2], nh = 0;
  int kwv[2], iwv[2], nw = 0;
  #pragma unroll
  for (int j = 0; j < 2; j++) {
    int kd = ((od + 1) & 1) + 2 * j;
    int num = od + 1 - kd;
    if (num >= 0 && (num >> 1) < 4) { kdv[nd] = kd; idv[nd] = num >> 1; nd++; }
    int kh = ((oh + 1) & 1) + 2 * j;
    num = oh + 1 - kh;
    if (num >= 0 && (num >> 1) < 32) { khv[nh] = kh; ihv[nh] = num >> 1; nh++; }
    int kw = ((ow + 1) & 1) + 2 * j;
    num = ow + 1 - kw;
    if (num >= 0 && (num >> 1) < 32) { kwv[nw] = kw; iwv[nw] = num >> 1; nw++; }
  }
  float acc = bias[co];
  for (int ci = 0; ci < 16; ci++) {
    const float* ip = q + ((n * 16 + ci) * 4) * 1024;
    const float* wp = w + ((ci * 8 + co) * 64);
    for (int a = 0; a < nd; a++)
      for (int b = 0; b < nh; b++)
        for (int c = 0; c < nw; c++)
          acc += ip[idv[a] * 1024 + ihv[b] * 32 + iwv[c]] *
                 wp[kdv[a] * 16 + khv[b] * 4 + kwv[c]];
  }
  d1[idx] = fmaxf(acc, 0.0f);
}

// deconv3: ConvTranspose3d(8->4, k4, s2, p1): d1 (16,8,8,64,64) -> d2 (16,4,16,128,128)
__global__ __launch_bounds__(256) void deconv3_k(
    const float* __restrict__ d1, const float* __restrict__ w,
    const float* __restrict__ bias, float* __restrict__ d2) {
  int idx = blockIdx.x * blockDim.x + threadIdx.x;
  const int total = NB * 4 * 16 * 128 * 128;
  if (idx >= total) return;
  int ow = idx & 127; int t = idx >> 7;
  int oh = t & 127; t >>= 7;
  int od = t & 15;  t >>= 4;
  int co = t & 3;   int n = t >> 2;

  int kdv[2], idv[2], nd = 0;
  int khv[2], ihv[2], nh = 0;
  int kwv[2], iwv[2], nw = 0;
  #pragma unroll
  for (int j = 0; j < 2; j++) {
    int kd = ((od + 1) & 1) + 2 * j;
    int num = od + 1 - kd;
    if (num >= 0 && (num >> 1) < 8) { kdv[nd] = kd; idv[nd] = num >> 1; nd++; }
    int kh = ((oh + 1) & 1) + 2 * j;
    num = oh + 1 - kh;
    if (num >= 0 && (num >> 1) < 64) { khv[nh] = kh; ihv[nh] = num >> 1; nh++; }
    int kw = ((ow + 1) & 1) + 2 * j;
    num = ow + 1 - kw;
    if (num >= 0 && (num >> 1) < 64) { kwv[nw] = kw; iwv[nw] = num >> 1; nw++; }
  }
  float acc = bias[co];
  for (int ci = 0; ci < 8; ci++) {
    const float* ip = d1 + ((n * 8 + ci) * 8) * 4096;
    const float* wp = w + ((ci * 4 + co) * 64);
    for (int a = 0; a < nd; a++)
      for (int b = 0; b < nh; b++)
        for (int c = 0; c < nw; c++)
          acc += ip[idv[a] * 4096 + ihv[b] * 64 + iwv[c]] *
                 wp[kdv[a] * 16 + khv[b] * 4 + kwv[c]];
  }
  d2[idx] = fmaxf(acc, 0.0f);
}

// deconv4: ConvTranspose3d(4->3, k3, s1, p1): d2 (16,4,16,128,128) -> out (16,3,16,128,128)
__global__ __launch_bounds__(256) void deconv4_k(
    const float* __restrict__ d2, const float* __restrict__ w,
    const float* __restrict__ bias, float* __restrict__ out) {
  int idx = blockIdx.x * blockDim.x + threadIdx.x;
  const int total = NB * 3 * 16 * 128 * 128;
  if (idx >= total) return;
  int ow = idx & 127; int t = idx >> 7;
  int oh = t & 127; t >>= 7;
  int od = t & 15;  t >>= 4;
  int co = t % 3;   int n = t / 3;
  float acc = bias[co];
  for (int ci = 0; ci < 4; ci++) {
    const float* ip = d2 + ((n * 4 + ci) * 16) * 16384;
    const float* wp = w + ((ci * 3 + co) * 27);
    #pragma unroll
    for (int kd = 0; kd < 3; kd++) {
      int id = od + 1 - kd; if ((unsigned)id >= 16u) continue;
      #pragma unroll
      for (int kh = 0; kh < 3; kh++) {
        int ih = oh + 1 - kh; if ((unsigned)ih >= 128u) continue;
        #pragma unroll
        for (int kw = 0; kw < 3; kw++) {
          int iw = ow + 1 - kw; if ((unsigned)iw >= 128u) continue;
          acc += ip[id * 16384 + ih * 128 + iw] * wp[kd * 9 + kh * 3 + kw];
        }
      }
    }
  }
  out[idx] = acc;
}

extern "C" void kernel_launch(void* const* d_in, const int* in_sizes, int n_in,
                              void* d_out, int out_size, void* d_ws, size_t ws_size,
                              hipStream_t stream) {
  const float* x      = (const float*)d_in[0];
  // d_in[1] = epoch (int, ==60, branch is fixed)
  const float* enc_w1 = (const float*)d_in[2];
  const float* enc_b1 = (const float*)d_in[3];
  const float* enc_w2 = (const float*)d_in[4];
  const float* enc_b2 = (const float*)d_in[5];
  const float* enc_w4 = (const float*)d_in[6];
  const float* enc_b4 = (const float*)d_in[7];
  const float* dec_w1 = (const float*)d_in[8];
  const float* dec_b1 = (const float*)d_in[9];
  const float* dec_w3 = (const float*)d_in[10];
  const float* dec_b3 = (const float*)d_in[11];
  const float* dec_w4 = (const float*)d_in[12];
  const float* dec_b4 = (const float*)d_in[13];
  const float* emb    = (const float*)d_in[14];
  const float* csize  = (const float*)d_in[15];

  float* ws = (float*)d_ws;
  // ws layout (floats):
  float* stats = ws;                      // 64      (loss sum + 32-bin hist)
  float* quant = ws + 64;                 // 1,048,576
  float* z     = quant + 1048576;         // 1,048,576
  float* y2    = z + 1048576;             // 524,288
  float* y1    = y2 + 524288;             // 2,097,152 (dead after conv2)
  float* d1    = z;                       // 4,194,304 (reuses z/y2/y1, live w/ quant)
  float* d2    = ws + 64 + 1048576 + 4194304;  // 16,777,216 (after d1)

  float* out   = (float*)d_out;                        // 12,582,912
  float* out_loss  = out + 12582912;                   // 1
  float* out_codes = out_loss + 1;                     // 65,536
  float* out_perp  = out_codes + 65536;                // 1
  float* out_used  = out_perp + 1;                     // 1

  init_stats_k<<<1, 64, 0, stream>>>(stats);

  conv1_k<<<(NB * 4 * 8 * 64 * 64) / 256, 256, 0, stream>>>(x, enc_w1, enc_b1, y1);
  conv2_k<<<(NB * 8 * 4 * 32 * 32) / 256, 256, 0, stream>>>(y1, enc_w2, enc_b2, y2);
  conv4_k<<<(NB * 16 * 4 * 32 * 32) / 256, 256, 0, stream>>>(y2, enc_w4, enc_b4, z);

  vq_k<<<65536 / 256, 256, 0, stream>>>(z, emb, quant, out_codes, stats);
  fin_k<<<1, 64, 0, stream>>>(stats, csize, out_loss, out_perp, out_used);

  deconv1_k<<<(NB * 8 * 8 * 64 * 64) / 256, 256, 0, stream>>>(quant, dec_w1, dec_b1, d1);
  deconv3_k<<<(NB * 4 * 16 * 128 * 128) / 256, 256, 0, stream>>>(d1, dec_w3, dec_b3, d2);
  deconv4_k<<<(NB * 3 * 16 * 128 * 128) / 256, 256, 0, stream>>>(d2, dec_w4, dec_b4, out);
}

// Round 2
// 497.040 us; speedup vs baseline: 3.2655x; 3.2655x over previous
//
#include <hip/hip_runtime.h>
#include <math.h>

#define NB 16

// ---------------- shapes ----------------
// x:      (16, 3,16,128,128)
// y1:     (16, 4, 8, 64, 64)   conv1 k4 s2 p1 + relu
// y2:     (16, 8, 4, 32, 32)   conv2 k4 s2 p1 + relu
// z:      (16,16, 4, 32, 32)   conv4 k3 s1 p1 + clip(0,6)
// quant:  (16,16, 4, 32, 32)   VQ
// d1:     (16, 8, 8, 64, 64)   deconv1 k4 s2 p1 + relu
// d2:     (16, 4,16,128,128)   deconv3 k4 s2 p1 + relu
// out:    (16, 3,16,128,128)   deconv4 k3 s1 p1

// conv1: thread computes 1 od x 2x2 (oh,ow) x 4 co. 131072 threads.
__global__ __launch_bounds__(256) void conv1_k(
    const float* __restrict__ x, const float* __restrict__ w,
    const float* __restrict__ bias, float* __restrict__ y) {
  int idx = blockIdx.x * 256 + threadIdx.x;
  int c = idx & 31;          // ow = 2c+pw
  int b = (idx >> 5) & 31;   // oh = 2b+ph
  int od = (idx >> 10) & 7;
  int n = idx >> 13;
  float acc[2][2][4];
  #pragma unroll
  for (int ph = 0; ph < 2; ph++)
    #pragma unroll
    for (int pw = 0; pw < 2; pw++)
      #pragma unroll
      for (int co = 0; co < 4; co++) acc[ph][pw][co] = bias[co];
  int id0 = 2 * od - 1, ih0 = 4 * b - 1, iw0 = 4 * c - 1;
  bool vh[6], vw[6];
  #pragma unroll
  for (int l = 0; l < 6; l++) {
    vh[l] = (unsigned)(ih0 + l) < 128u;
    vw[l] = (unsigned)(iw0 + l) < 128u;
  }
  #pragma unroll 1
  for (int ci = 0; ci < 3; ci++) {
    const float* xp = x + ((n * 3 + ci) * 16) * 16384;
    #pragma unroll
    for (int kd = 0; kd < 4; kd++) {
      int id = id0 + kd;
      bool vd = (unsigned)id < 16u;
      const float* pp = xp + id * 16384;
      float p[6][6];
      #pragma unroll
      for (int lh = 0; lh < 6; lh++)
        #pragma unroll
        for (int lw = 0; lw < 6; lw++)
          p[lh][lw] = (vd && vh[lh] && vw[lw]) ? pp[(ih0 + lh) * 128 + (iw0 + lw)] : 0.0f;
      #pragma unroll
      for (int co = 0; co < 4; co++) {
        const float* wp = w + ((co * 3 + ci) * 4 + kd) * 16;
        #pragma unroll
        for (int kh = 0; kh < 4; kh++)
          #pragma unroll
          for (int kw = 0; kw < 4; kw++) {
            float wv = wp[kh * 4 + kw];
            #pragma unroll
            for (int ph = 0; ph < 2; ph++)
              #pragma unroll
              for (int pw = 0; pw < 2; pw++)
                acc[ph][pw][co] += p[2 * ph + kh][2 * pw + kw] * wv;
          }
      }
    }
  }
  #pragma unroll
  for (int co = 0; co < 4; co++)
    #pragma unroll
    for (int ph = 0; ph < 2; ph++)
      #pragma unroll
      for (int pw = 0; pw < 2; pw++)
        y[((n * 4 + co) * 8 + od) * 4096 + (2 * b + ph) * 64 + (2 * c + pw)] =
            fmaxf(acc[ph][pw][co], 0.0f);
}

// conv2: thread = 1 pos x 8 co. 65536 threads.
__global__ __launch_bounds__(256) void conv2_k(
    const float* __restrict__ y1, const float* __restrict__ w,
    const float* __restrict__ bias, float* __restrict__ y) {
  int idx = blockIdx.x * 256 + threadIdx.x;
  int ow = idx & 31;
  int oh = (idx >> 5) & 31;
  int od = (idx >> 10) & 3;
  int n = idx >> 12;
  float acc[8];
  #pragma unroll
  for (int co = 0; co < 8; co++) acc[co] = bias[co];
  int id0 = 2 * od - 1, ih0 = 2 * oh - 1, iw0 = 2 * ow - 1;
  bool vh[4], vw[4];
  #pragma unroll
  for (int l = 0; l < 4; l++) {
    vh[l] = (unsigned)(ih0 + l) < 64u;
    vw[l] = (unsigned)(iw0 + l) < 64u;
  }
  #pragma unroll 1
  for (int ci = 0; ci < 4; ci++) {
    const float* ip = y1 + ((n * 4 + ci) * 8) * 4096;
    #pragma unroll
    for (int kd = 0; kd < 4; kd++) {
      int id = id0 + kd;
      bool vd = (unsigned)id < 8u;
      const float* pp = ip + id * 4096;
      float p[4][4];
      #pragma unroll
      for (int kh = 0; kh < 4; kh++)
        #pragma unroll
        for (int kw = 0; kw < 4; kw++)
          p[kh][kw] = (vd && vh[kh] && vw[kw]) ? pp[(ih0 + kh) * 64 + (iw0 + kw)] : 0.0f;
      #pragma unroll
      for (int co = 0; co < 8; co++) {
        const float* wp = w + ((co * 4 + ci) * 4 + kd) * 16;
        #pragma unroll
        for (int kh = 0; kh < 4; kh++)
          #pragma unroll
          for (int kw = 0; kw < 4; kw++)
            acc[co] += p[kh][kw] * wp[kh * 4 + kw];
      }
    }
  }
  #pragma unroll
  for (int co = 0; co < 8; co++)
    y[((n * 8 + co) * 4 + od) * 1024 + oh * 32 + ow] = fmaxf(acc[co], 0.0f);
}

// conv4: thread = 1 pos x 16 co. 65536 threads.
__global__ __launch_bounds__(256) void conv4_k(
    const float* __restrict__ y2, const float* __restrict__ w,
    const float* __restrict__ bias, float* __restrict__ z) {
  int idx = blockIdx.x * 256 + threadIdx.x;
  int ow = idx & 31;
  int oh = (idx >> 5) & 31;
  int od = (idx >> 10) & 3;
  int n = idx >> 12;
  float acc[16];
  #pragma unroll
  for (int co = 0; co < 16; co++) acc[co] = bias[co];
  bool vh[3], vw[3];
  #pragma unroll
  for (int l = 0; l < 3; l++) {
    vh[l] = (unsigned)(oh - 1 + l) < 32u;
    vw[l] = (unsigned)(ow - 1 + l) < 32u;
  }
  #pragma unroll 1
  for (int ci = 0; ci < 8; ci++) {
    const float* ip = y2 + ((n * 8 + ci) * 4) * 1024;
    #pragma unroll
    for (int kd = 0; kd < 3; kd++) {
      int id = od - 1 + kd;
      bool vd = (unsigned)id < 4u;
      const float* pp = ip + id * 1024;
      float p[3][3];
      #pragma unroll
      for (int kh = 0; kh < 3; kh++)
        #pragma unroll
        for (int kw = 0; kw < 3; kw++)
          p[kh][kw] = (vd && vh[kh] && vw[kw]) ? pp[(oh - 1 + kh) * 32 + (ow - 1 + kw)] : 0.0f;
      #pragma unroll
      for (int co = 0; co < 16; co++) {
        const float* wp = w + ((co * 8 + ci) * 3 + kd) * 9;
        #pragma unroll
        for (int kh = 0; kh < 3; kh++)
          #pragma unroll
          for (int kw = 0; kw < 3; kw++)
            acc[co] += p[kh][kw] * wp[kh * 3 + kw];
      }
    }
  }
  #pragma unroll
  for (int co = 0; co < 16; co++)
    z[((n * 16 + co) * 4 + od) * 1024 + oh * 32 + ow] =
        fminf(fmaxf(acc[co], 0.0f), 6.0f);
}

// VQ: one thread per spatial location. stats[0]=loss sum, stats[1..32]=hist.
__global__ __launch_bounds__(256) void vq_k(
    const float* __restrict__ z, const float* __restrict__ emb,
    float* __restrict__ quant, float* __restrict__ codes_out,
    float* __restrict__ stats) {
  __shared__ float se[32 * 16];
  __shared__ float se2[32];
  __shared__ float shist[32];
  __shared__ float swred[4];
  int tid = threadIdx.x;
  for (int i = tid; i < 512; i += 256) {
    int r = i >> 4;
    float v = emb[i];
    if (r == 0) v = 0.0f;
    else if (r == 1) v = 6.0f;
    se[i] = v;
  }
  if (tid < 32) shist[tid] = 0.0f;
  __syncthreads();
  if (tid < 32) {
    float s = 0.0f;
    #pragma unroll
    for (int d = 0; d < 16; d++) { float v = se[tid * 16 + d]; s += v * v; }
    se2[tid] = s;
  }
  __syncthreads();

  int idx = blockIdx.x * 256 + tid;
  float lsum = 0.0f;
  {
    int w_ = idx & 31; int t = idx >> 5;
    int h_ = t & 31; t >>= 5;
    int d_ = t & 3;  int b_ = t >> 2;
    const float* zp = z + b_ * 65536 + d_ * 1024 + h_ * 32 + w_;
    float f[16];
    float f2 = 0.0f;
    #pragma unroll
    for (int c = 0; c < 16; c++) { float v = zp[c * 4096]; f[c] = v; f2 += v * v; }
    float best = 1e30f; int bi = 0;
    for (int e = 0; e < 32; e++) {
      float dot = 0.0f;
      #pragma unroll
      for (int c = 0; c < 16; c++) dot += f[c] * se[e * 16 + c];
      float d2 = f2 - 2.0f * dot + se2[e];
      if (d2 < best) { best = d2; bi = e; }
    }
    float* qp = quant + b_ * 65536 + d_ * 1024 + h_ * 32 + w_;
    #pragma unroll
    for (int c = 0; c < 16; c++) {
      float q = se[bi * 16 + c];
      qp[c * 4096] = q;
      float df = q - f[c];
      lsum += df * df;
    }
    codes_out[idx] = (float)bi;
    atomicAdd(&shist[bi], 1.0f);
  }
  for (int o = 32; o; o >>= 1) lsum += __shfl_down(lsum, o);
  if ((tid & 63) == 0) swred[tid >> 6] = lsum;
  __syncthreads();
  if (tid == 0) atomicAdd(&stats[0], swred[0] + swred[1] + swred[2] + swred[3]);
  if (tid < 32) {
    float h = shist[tid];
    if (h != 0.0f) atomicAdd(&stats[1 + tid], h);
  }
}

__global__ void init_stats_k(float* __restrict__ stats) {
  int tid = threadIdx.x;
  if (tid < 33) stats[tid] = 0.0f;
}

__global__ void fin_k(const float* __restrict__ stats,
                      const float* __restrict__ cluster_size,
                      float* __restrict__ out_loss, float* __restrict__ out_perp,
                      float* __restrict__ out_used) {
  int tid = threadIdx.x;
  float v = 0.0f;
  float used = 0.0f;
  if (tid < 32) {
    float p = stats[1 + tid] * (1.0f / 65536.0f);
    v = p * logf(p + 1e-10f);
    used = (cluster_size[tid] > 1e-5f) ? 1.0f : 0.0f;
  }
  for (int o = 16; o; o >>= 1) { v += __shfl_down(v, o); used += __shfl_down(used, o); }
  if (tid == 0) {
    *out_perp = expf(-v);
    *out_used = used * (1.0f / 32.0f);
    *out_loss = 0.25f * stats[0] * (1.0f / 1048576.0f);
  }
}

// Parity tap tables for k=4, s=2, p=1 transposed conv:
// output phase p uses taps (kd, local-input-index li) per j in {0,1}:
//   p=0: (1,1),(3,0)    p=1: (0,2),(2,1)        (li is id-(a-1), a = out-pair idx)

// deconv1: quant (16,16,4,32,32) -> d1 (16,8,8,64,64). Thread: 2x2x2 pos x 4 co
// (co group from grid). 131072 threads.
__global__ __launch_bounds__(256) void deconv1_k(
    const float* __restrict__ q, const float* __restrict__ w,
    const float* __restrict__ bias, float* __restrict__ d1) {
  const int KD[2][2] = {{1, 3}, {0, 2}};
  const int LI[2][2] = {{1, 0}, {2, 1}};
  int idx = blockIdx.x * 256 + threadIdx.x;
  int c = idx & 31;
  int b = (idx >> 5) & 31;
  int a = (idx >> 10) & 3;
  int n = (idx >> 12) & 15;
  int cog = idx >> 16;  // 0 or 1
  float acc[2][2][2][4];
  #pragma unroll
  for (int pd = 0; pd < 2; pd++)
    #pragma unroll
    for (int ph = 0; ph < 2; ph++)
      #pragma unroll
      for (int pw = 0; pw < 2; pw++)
        #pragma unroll
        for (int co = 0; co < 4; co++) acc[pd][ph][pw][co] = bias[cog * 4 + co];
  bool vd[3], vh[3], vw[3];
  #pragma unroll
  for (int l = 0; l < 3; l++) {
    vd[l] = (unsigned)(a - 1 + l) < 4u;
    vh[l] = (unsigned)(b - 1 + l) < 32u;
    vw[l] = (unsigned)(c - 1 + l) < 32u;
  }
  #pragma unroll 1
  for (int ci = 0; ci < 16; ci++) {
    const float* ip = q + ((n * 16 + ci) * 4) * 1024;
    float in[3][3][3];
    #pragma unroll
    for (int ld = 0; ld < 3; ld++)
      #pragma unroll
      for (int lh = 0; lh < 3; lh++)
        #pragma unroll
        for (int lw = 0; lw < 3; lw++)
          in[ld][lh][lw] = (vd[ld] && vh[lh] && vw[lw])
              ? ip[(a - 1 + ld) * 1024 + (b - 1 + lh) * 32 + (c - 1 + lw)] : 0.0f;
    #pragma unroll
    for (int pd = 0; pd < 2; pd++)
      #pragma unroll
      for (int jd = 0; jd < 2; jd++) {
        int kd = KD[pd][jd], ld = LI[pd][jd];
        #pragma unroll
        for (int ph = 0; ph < 2; ph++)
          #pragma unroll
          for (int jh = 0; jh < 2; jh++) {
            int kh = KD[ph][jh], lh = LI[ph][jh];
            #pragma unroll
            for (int pw = 0; pw < 2; pw++)
              #pragma unroll
              for (int jw = 0; jw < 2; jw++) {
                int kw = KD[pw][jw], lw = LI[pw][jw];
                float iv = in[ld][lh][lw];
                #pragma unroll
                for (int co = 0; co < 4; co++)
                  acc[pd][ph][pw][co] +=
                      iv * w[((ci * 8 + cog * 4 + co) * 4 + kd) * 16 + kh * 4 + kw];
              }
          }
      }
  }
  #pragma unroll
  for (int co = 0; co < 4; co++)
    #pragma unroll
    for (int pd = 0; pd < 2; pd++)
      #pragma unroll
      for (int ph = 0; ph < 2; ph++)
        #pragma unroll
        for (int pw = 0; pw < 2; pw++)
          d1[((n * 8 + cog * 4 + co) * 8 + 2 * a + pd) * 4096 +
             (2 * b + ph) * 64 + (2 * c + pw)] = fmaxf(acc[pd][ph][pw][co], 0.0f);
}

// deconv3: d1 (16,8,8,64,64) -> d2 (16,4,16,128,128). Thread: 2x2x2 pos x 4 co.
// 524288 threads.
__global__ __launch_bounds__(256) void deconv3_k(
    const float* __restrict__ d1, const float* __restrict__ w,
    const float* __restrict__ bias, float* __restrict__ d2) {
  const int KD[2][2] = {{1, 3}, {0, 2}};
  const int LI[2][2] = {{1, 0}, {2, 1}};
  int idx = blockIdx.x * 256 + threadIdx.x;
  int c = idx & 63;
  int b = (idx >> 6) & 63;
  int a = (idx >> 12) & 7;
  int n = idx >> 15;
  float acc[2][2][2][4];
  #pragma unroll
  for (int pd = 0; pd < 2; pd++)
    #pragma unroll
    for (int ph = 0; ph < 2; ph++)
      #pragma unroll
      for (int pw = 0; pw < 2; pw++)
        #pragma unroll
        for (int co = 0; co < 4; co++) acc[pd][ph][pw][co] = bias[co];
  bool vd[3], vh[3], vw[3];
  #pragma unroll
  for (int l = 0; l < 3; l++) {
    vd[l] = (unsigned)(a - 1 + l) < 8u;
    vh[l] = (unsigned)(b - 1 + l) < 64u;
    vw[l] = (unsigned)(c - 1 + l) < 64u;
  }
  #pragma unroll 1
  for (int ci = 0; ci < 8; ci++) {
    const float* ip = d1 + ((n * 8 + ci) * 8) * 4096;
    float in[3][3][3];
    #pragma unroll
    for (int ld = 0; ld < 3; ld++)
      #pragma unroll
      for (int lh = 0; lh < 3; lh++)
        #pragma unroll
        for (int lw = 0; lw < 3; lw++)
          in[ld][lh][lw] = (vd[ld] && vh[lh] && vw[lw])
              ? ip[(a - 1 + ld) * 4096 + (b - 1 + lh) * 64 + (c - 1 + lw)] : 0.0f;
    #pragma unroll
    for (int pd = 0; pd < 2; pd++)
      #pragma unroll
      for (int jd = 0; jd < 2; jd++) {
        int kd = KD[pd][jd], ld = LI[pd][jd];
        #pragma unroll
        for (int ph = 0; ph < 2; ph++)
          #pragma unroll
          for (int jh = 0; jh < 2; jh++) {
            int kh = KD[ph][jh], lh = LI[ph][jh];
            #pragma unroll
            for (int pw = 0; pw < 2; pw++)
              #pragma unroll
              for (int jw = 0; jw < 2; jw++) {
                int kw = KD[pw][jw], lw = LI[pw][jw];
                float iv = in[ld][lh][lw];
                #pragma unroll
                for (int co = 0; co < 4; co++)
                  acc[pd][ph][pw][co] +=
                      iv * w[((ci * 4 + co) * 4 + kd) * 16 + kh * 4 + kw];
              }
          }
      }
  }
  #pragma unroll
  for (int co = 0; co < 4; co++)
    #pragma unroll
    for (int pd = 0; pd < 2; pd++)
      #pragma unroll
      for (int ph = 0; ph < 2; ph++)
        #pragma unroll
        for (int pw = 0; pw < 2; pw++)
          d2[((n * 4 + co) * 16 + 2 * a + pd) * 16384 +
             (2 * b + ph) * 128 + (2 * c + pw)] = fmaxf(acc[pd][ph][pw][co], 0.0f);
}

// deconv4: d2 (16,4,16,128,128) -> out (16,3,16,128,128), k3 s1 p1.
// Thread: 2x2x2 pos x 3 co. 524288 threads.
// taps: kd = pd+2-ld (valid 0..2), local input li = id-(2a-1) in 0..3.
__global__ __launch_bounds__(256) void deconv4_k(
    const float* __restrict__ d2, const float* __restrict__ w,
    const float* __restrict__ bias, float* __restrict__ out) {
  int idx = blockIdx.x * 256 + threadIdx.x;
  int c = idx & 63;
  int b = (idx >> 6) & 63;
  int a = (idx >> 12) & 7;
  int n = idx >> 15;
  float acc[2][2][2][3];
  #pragma unroll
  for (int pd = 0; pd < 2; pd++)
    #pragma unroll
    for (int ph = 0; ph < 2; ph++)
      #pragma unroll
      for (int pw = 0; pw < 2; pw++)
        #pragma unroll
        for (int co = 0; co < 3; co++) acc[pd][ph][pw][co] = bias[co];
  int ih0 = 2 * b - 1, iw0 = 2 * c - 1;
  bool vh[4], vw[4];
  #pragma unroll
  for (int l = 0; l < 4; l++) {
    vh[l] = (unsigned)(ih0 + l) < 128u;
    vw[l] = (unsigned)(iw0 + l) < 128u;
  }
  #pragma unroll 1
  for (int ci = 0; ci < 4; ci++) {
    const float* ip = d2 + ((n * 4 + ci) * 16) * 16384;
    #pragma unroll
    for (int ld = 0; ld < 4; ld++) {
      int id = 2 * a - 1 + ld;
      bool vdl = (unsigned)id < 16u;
      const float* pp = ip + id * 16384;
      float p[4][4];
      #pragma unroll
      for (int lh = 0; lh < 4; lh++)
        #pragma unroll
        for (int lw = 0; lw < 4; lw++)
          p[lh][lw] = (vdl && vh[lh] && vw[lw]) ? pp[(ih0 + lh) * 128 + (iw0 + lw)] : 0.0f;
      #pragma unroll
      for (int pd = 0; pd < 2; pd++) {
        int kd = pd + 2 - ld;
        if (kd < 0 || kd > 2) continue;
        #pragma unroll
        for (int kh = 0; kh < 3; kh++)
          #pragma unroll
          for (int kw = 0; kw < 3; kw++)
            #pragma unroll
            for (int co = 0; co < 3; co++) {
              float wv = w[(ci * 3 + co) * 27 + kd * 9 + kh * 3 + kw];
              #pragma unroll
              for (int ph = 0; ph < 2; ph++)
                #pragma unroll
                for (int pw = 0; pw < 2; pw++)
                  acc[pd][ph][pw][co] += p[ph + 2 - kh][pw + 2 - kw] * wv;
            }
      }
    }
  }
  #pragma unroll
  for (int co = 0; co < 3; co++)
    #pragma unroll
    for (int pd = 0; pd < 2; pd++)
      #pragma unroll
      for (int ph = 0; ph < 2; ph++)
        #pragma unroll
        for (int pw = 0; pw < 2; pw++)
          out[((n * 3 + co) * 16 + 2 * a + pd) * 16384 +
              (2 * b + ph) * 128 + (2 * c + pw)] = acc[pd][ph][pw][co];
}

extern "C" void kernel_launch(void* const* d_in, const int* in_sizes, int n_in,
                              void* d_out, int out_size, void* d_ws, size_t ws_size,
                              hipStream_t stream) {
  const float* x      = (const float*)d_in[0];
  const float* enc_w1 = (const float*)d_in[2];
  const float* enc_b1 = (const float*)d_in[3];
  const float* enc_w2 = (const float*)d_in[4];
  const float* enc_b2 = (const float*)d_in[5];
  const float* enc_w4 = (const float*)d_in[6];
  const float* enc_b4 = (const float*)d_in[7];
  const float* dec_w1 = (const float*)d_in[8];
  const float* dec_b1 = (const float*)d_in[9];
  const float* dec_w3 = (const float*)d_in[10];
  const float* dec_b3 = (const float*)d_in[11];
  const float* dec_w4 = (const float*)d_in[12];
  const float* dec_b4 = (const float*)d_in[13];
  const float* emb    = (const float*)d_in[14];
  const float* csize  = (const float*)d_in[15];

  float* ws = (float*)d_ws;
  float* stats = ws;                      // 64
  float* quant = ws + 64;                 // 1,048,576
  float* z     = quant + 1048576;         // 1,048,576
  float* y2    = z + 1048576;             // 524,288
  float* y1    = y2 + 524288;             // 2,097,152 (dead after conv2)
  float* d1    = z;                       // 4,194,304 (reuses z/y2/y1)
  float* d2    = ws + 64 + 1048576 + 4194304;  // 16,777,216

  float* out   = (float*)d_out;                        // 12,582,912
  float* out_loss  = out + 12582912;
  float* out_codes = out_loss + 1;                     // 65,536
  float* out_perp  = out_codes + 65536;
  float* out_used  = out_perp + 1;

  init_stats_k<<<1, 64, 0, stream>>>(stats);

  conv1_k<<<512, 256, 0, stream>>>(x, enc_w1, enc_b1, y1);
  conv2_k<<<256, 256, 0, stream>>>(y1, enc_w2, enc_b2, y2);
  conv4_k<<<256, 256, 0, stream>>>(y2, enc_w4, enc_b4, z);

  vq_k<<<256, 256, 0, stream>>>(z, emb, quant, out_codes, stats);
  fin_k<<<1, 64, 0, stream>>>(stats, csize, out_loss, out_perp, out_used);

  deconv1_k<<<512, 256, 0, stream>>>(quant, dec_w1, dec_b1, d1);
  deconv3_k<<<2048, 256, 0, stream>>>(d1, dec_w3, dec_b3, d2);
  deconv4_k<<<2048, 256, 0, stream>>>(d2, dec_w4, dec_b4, out);
}